// Round 1
// baseline (82.239 us; speedup 1.0000x reference)
//
#include <hip/hip_runtime.h>

#ifndef __has_builtin
#define __has_builtin(x) 0
#endif

// Problem constants (from reference): B, CIN, H, W = 8, 1, 192, 192; COUT, KH, KW = 8, 7, 7
constexpr int B_    = 8;
constexpr int H_    = 192;
constexpr int W_    = 192;
constexpr int COUT_ = 8;
constexpr int KH_   = 7;
constexpr int KW_   = 7;
constexpr int HO_   = H_ - KH_ + 1;  // 186
constexpr int WO_   = W_ - KW_ + 1;  // 186

__device__ __forceinline__ float fast_exp2(float v) {
#if __has_builtin(__builtin_amdgcn_exp2f)
    return __builtin_amdgcn_exp2f(v);   // v_exp_f32
#else
    return exp2f(v);
#endif
}

// One thread per output pixel (oy, ox); loops over the 8 COUT channels with the
// 7x7 input window held in registers (reused across channels).
// block = 32x8 so each wave covers 2 contiguous rows of 32 -> coalesced x loads
// and out stores. filt/alpha are read with block-uniform indices -> scalar loads.
__global__ __launch_bounds__(256) void smorph_kernel(
    const float* __restrict__ x,      // (B, 1, H, W)
    const float* __restrict__ filt,   // (COUT, 1, KH, KW)
    const float* __restrict__ alpha,  // (COUT, 1)
    float* __restrict__ out)          // (B, COUT, HO, WO)
{
    const int ox = blockIdx.x * 32 + threadIdx.x;
    const int oy = blockIdx.y * 8  + threadIdx.y;
    const int b  = blockIdx.z;
    if (ox >= WO_ || oy >= HO_) return;

    const float* xb = x + b * (H_ * W_);

    // Load 7x7 window into registers once; reused for all 8 output channels.
    float win[KH_ * KW_];
#pragma unroll
    for (int ky = 0; ky < KH_; ++ky) {
#pragma unroll
        for (int kx = 0; kx < KW_; ++kx) {
            win[ky * KW_ + kx] = xb[(oy + ky) * W_ + (ox + kx)];
        }
    }

    constexpr float LOG2E = 1.44269504088896340736f;

#pragma unroll 1   // keep channel loop rolled: bounds SGPR pressure, code size
    for (int c = 0; c < COUT_; ++c) {
        const float a   = alpha[c];        // uniform -> s_load
        const float al2 = a * LOG2E;       // fold log2(e) so exp is a bare v_exp_f32
        float num = 0.0f;
        float den = 0.0f;
#pragma unroll
        for (int k = 0; k < KH_ * KW_; ++k) {
            const float f = filt[c * (KH_ * KW_) + k];  // uniform -> s_load
            const float s = win[k] + f;
            const float e = fast_exp2(al2 * s);         // exp(a*s)
            num = __builtin_fmaf(s, e, num);
            den += e;
        }
        out[((b * COUT_ + c) * HO_ + oy) * WO_ + ox] = num / den;
    }
}

extern "C" void kernel_launch(void* const* d_in, const int* in_sizes, int n_in,
                              void* d_out, int out_size, void* d_ws, size_t ws_size,
                              hipStream_t stream) {
    const float* x     = (const float*)d_in[0];
    const float* filt  = (const float*)d_in[1];
    const float* alpha = (const float*)d_in[2];
    float* out = (float*)d_out;

    dim3 block(32, 8, 1);
    dim3 grid((WO_ + 31) / 32, (HO_ + 7) / 8, B_);  // (6, 24, 8)
    smorph_kernel<<<grid, block, 0, stream>>>(x, filt, alpha, out);
}